// Round 5
// baseline (127.378 us; speedup 1.0000x reference)
//
#include <hip/hip_runtime.h>
#include <math.h>

// fab_penalty_ls_curve: curvature penalty over mirrored level-set field.
// R5: 4-column float4 vectorization (11 VMEM / 4 points vs 13 / point),
// on top of R4's proven structure: fast math (v_rcp/v_sqrt/minimax atan),
// interior/boundary template split in rows, plain per-block partial stores
// -> tiny finish kernel (NO device-scope atomics — R2/R3's 3x regression).
// Mirror-half trick (verified absmax 0.0): compute left half only, x2.

#define BLOCK_X 256
#define ROWS_PER 8
#define COLS_PER 4

// atan(v / c) with v > 0, given rv ~= 1/v (reused from k = num*rv^3).
// Max abs error ~1e-5 rad; error budget is ~1e3x larger (2% on the sum).
__device__ __forceinline__ float fast_atan_ratio(float v, float c, float rv)
{
    const float rc = __builtin_amdgcn_rcpf(c);
    const float q  = v * rc;        // v/c (sign = sign(c))
    const float iq = c * rv;        // c/v = 1/q, no extra rcp
    const bool  big = fabsf(q) > 1.0f;
    const float t  = big ? iq : q;
    const float s  = t * t;
    float p = fmaf(s, -0.01172120f, 0.05265332f);
    p = fmaf(s, p, -0.11643287f);
    p = fmaf(s, p,  0.19354346f);
    p = fmaf(s, p, -0.33262347f);
    p = fmaf(s, p,  0.99997726f);
    const float at = p * t;
    const float hp = copysignf(1.57079632679f, q);
    return big ? (hp - at) : at;    // atan(q) = sign(q)*pi/2 - atan(1/q), |q|>1
}

// Interior-column 4-wide path. j0 multiple of 4, 4 <= j0 <= Wn-8, so all
// column neighbors are direct (no clamp, no mirror) and sy* == rd2.
template<bool INT>
__device__ __forceinline__ float vec4_cols(
    const float* __restrict__ eps, int Hn, int Wn, int i0, int j0, float rd)
{
    const float rd2 = 0.5f * rd;
    const float SC = 1e-12f;
    const float FLOORV = (float)(1e-32 / 6.0);
    const float pi_d = 3.14159265358979323846f / 1.1f;

    float acc = 0.0f;
    for (int r = 0; r < ROWS_PER; ++r) {
        const int i = i0 + r;
        if (!INT && i >= Hn) break;
        int im, ip, imm, ipp;
        float sxi, sxm, sxp;
        if (INT) {
            im = i - 1; ip = i + 1; imm = i - 2; ipp = i + 2;
            sxi = rd2; sxm = rd2; sxp = rd2;
        } else {
            im  = (i > 0) ? i - 1 : 0;
            ip  = (i < Hn - 1) ? i + 1 : Hn - 1;
            imm = (im > 0) ? im - 1 : 0;
            ipp = (ip < Hn - 1) ? ip + 1 : Hn - 1;
            sxi = (i == 0 || i == Hn - 1) ? rd : rd2;
            sxm = (im == 0) ? rd : rd2;
            sxp = (ip == Hn - 1) ? rd : rd2;
        }
        const float* rc  = eps + (size_t)i   * (size_t)Wn;
        const float* rm  = eps + (size_t)im  * (size_t)Wn;
        const float* rp  = eps + (size_t)ip  * (size_t)Wn;
        const float* rmm = eps + (size_t)imm * (size_t)Wn;
        const float* rpp = eps + (size_t)ipp * (size_t)Wn;

        // 5 aligned float4 + 2 float2 + 4 scalar = 11 VMEM for 4 points
        const float4 aNN = *(const float4*)(rmm + j0);
        const float4 aM  = *(const float4*)(rm  + j0);
        const float4 aC  = *(const float4*)(rc  + j0);
        const float4 aP  = *(const float4*)(rp  + j0);
        const float4 aSS = *(const float4*)(rpp + j0);
        const float2 cL  = *(const float2*)(rc + j0 - 2);   // 8B-aligned
        const float2 cR  = *(const float2*)(rc + j0 + 4);
        const float mL = rm[j0 - 1], mR = rm[j0 + 4];
        const float pL = rp[j0 - 1], pR = rp[j0 + 4];

        const float C[8]  = {cL.x, cL.y, aC.x, aC.y, aC.z, aC.w, cR.x, cR.y};
        const float M[6]  = {mL, aM.x, aM.y, aM.z, aM.w, mR};
        const float P[6]  = {pL, aP.x, aP.y, aP.z, aP.w, pR};
        const float NN[4] = {aNN.x, aNN.y, aNN.z, aNN.w};
        const float SS[4] = {aSS.x, aSS.y, aSS.z, aSS.w};

        #pragma unroll
        for (int x = 0; x < 4; ++x) {
            const float e_c = C[x + 2];
            const float ex  = fmaf(P[x + 1] - M[x + 1], sxi, SC);
            const float ey  = fmaf(C[x + 3] - C[x + 1], rd2, SC);
            float exn = fmaf(e_c - NN[x], sxm, SC);
            float exs = fmaf(SS[x] - e_c, sxp, SC);
            if (!INT) {
                if (i == 0)      exn = ex;   // im == i at top boundary
                if (i == Hn - 1) exs = ex;   // ip == i at bottom boundary
            }
            const float exx = (exs - exn) * sxi;
            const float eyw = fmaf(e_c - C[x], rd2, SC);
            const float eye = fmaf(C[x + 4] - e_c, rd2, SC);
            const float eyy = (eye - eyw) * rd2;
            const float exy = ((P[x + 2] - M[x + 2]) - (P[x] - M[x])) * (sxi * rd2);

            const float t1 = ex * ex;
            const float t2 = ey * ey;
            float num = t1 * eyy;
            num = fmaf(t2, exx, num);
            num = fmaf(-2.0f * (ex * ey), exy, num);

            float ev = __builtin_amdgcn_sqrtf(t1 + t2);
            ev = fmaxf(ev, FLOORV);
            const float rv = __builtin_amdgcn_rcpf(ev);
            const float k  = num * (rv * rv) * rv;
            const float at = fast_atan_ratio(ev, e_c, rv);
            const float cc = fabsf(k * at) - pi_d;
            acc += fmaxf(cc, 0.0f);      // fmax(NaN,0)=0 -> nansum semantics
        }
    }
    return acc;
}

// General scalar single-column path (col clamp + mirror + row clamp); used
// only for j0==0 and j0==Wn-4 threads (2 lanes out of 8192 waves).
__device__ float scalar_col(const float* __restrict__ eps, int Hn, int Wn,
                            int i0, int j, float rd)
{
    const float rd2 = 0.5f * rd;
    const float SC = 1e-12f;
    const float FLOORV = (float)(1e-32 / 6.0);
    const float pi_d = 3.14159265358979323846f / 1.1f;

    const int jm  = (j > 0) ? j - 1 : 0;
    const int jmm = (j > 1) ? j - 2 : 0;
    const int jp = j + 1, jpp = j + 2;
    const int cjp  = (jp  < Wn) ? jp  : (2 * Wn - 1 - jp);   // mirror seam
    const int cjpp = (jpp < Wn) ? jpp : (2 * Wn - 1 - jpp);
    const float syj = (j == 0)  ? rd : rd2;
    const float sym = (jm == 0) ? rd : rd2;
    const float syp = rd2;   // jp never a boundary of the 2W virtual grid

    float acc = 0.0f;
    for (int r = 0; r < ROWS_PER; ++r) {
        const int i = i0 + r;
        if (i >= Hn) break;
        const int im  = (i > 0) ? i - 1 : 0;
        const int ip  = (i < Hn - 1) ? i + 1 : Hn - 1;
        const int imm = (im > 0) ? im - 1 : 0;
        const int ipp = (ip < Hn - 1) ? ip + 1 : Hn - 1;
        const float sxi = (i == 0 || i == Hn - 1) ? rd : rd2;
        const float sxm = (im == 0) ? rd : rd2;
        const float sxp = (ip == Hn - 1) ? rd : rd2;

        const float* rowc  = eps + (size_t)i   * (size_t)Wn;
        const float* rown  = eps + (size_t)im  * (size_t)Wn;
        const float* rows_ = eps + (size_t)ip  * (size_t)Wn;
        const float* rownn = eps + (size_t)imm * (size_t)Wn;
        const float* rowss = eps + (size_t)ipp * (size_t)Wn;

        const float e_c  = rowc[j];
        const float e_n  = rown[j],   e_s  = rows_[j];
        const float e_nn = rownn[j],  e_ss = rowss[j];
        const float e_w  = rowc[jm],  e_e  = rowc[cjp];
        const float e_ww = rowc[jmm], e_ee = rowc[cjpp];
        const float e_nw = rown[jm],  e_ne = rown[cjp];
        const float e_sw = rows_[jm], e_se = rows_[cjp];

        const float ex = fmaf(e_s - e_n, sxi, SC);
        const float ey = fmaf(e_e - e_w, syj, SC);
        float exn = fmaf(e_c - e_nn, sxm, SC);
        float exs = fmaf(e_ss - e_c, sxp, SC);
        if (i == 0)      exn = ex;
        if (i == Hn - 1) exs = ex;
        const float exx = (exs - exn) * sxi;
        float eyw = fmaf(e_c - e_ww, sym, SC);
        const float eye = fmaf(e_ee - e_c, syp, SC);
        if (j == 0) eyw = ey;
        const float eyy = (eye - eyw) * syj;
        const float exy = ((e_se - e_ne) - (e_sw - e_nw)) * (sxi * syj);

        const float t1 = ex * ex;
        const float t2 = ey * ey;
        float num = t1 * eyy;
        num = fmaf(t2, exx, num);
        num = fmaf(-2.0f * (ex * ey), exy, num);

        float ev = __builtin_amdgcn_sqrtf(t1 + t2);
        ev = fmaxf(ev, FLOORV);
        const float rv = __builtin_amdgcn_rcpf(ev);
        const float k  = num * (rv * rv) * rv;
        const float at = fast_atan_ratio(ev, e_c, rv);
        const float cc = fabsf(k * at) - pi_d;
        acc += fmaxf(cc, 0.0f);
    }
    return acc;
}

__global__ __launch_bounds__(BLOCK_X, 4) void curve_partial_kernel(
    const float* __restrict__ eps, const float* __restrict__ gs,
    double* __restrict__ partial, int Hn, int Wn)
{
    const int tx = threadIdx.x;
    const int j0 = (blockIdx.x * BLOCK_X + tx) * COLS_PER;
    const int i0 = blockIdx.y * ROWS_PER;
    const float rd = 1.0f / gs[0];

    float accf = 0.0f;
    if (j0 < Wn) {
        const bool iint = (i0 >= 2) && (i0 + ROWS_PER + 1 < Hn);
        const bool jint = (j0 >= 4) && (j0 + 8 <= Wn);
        if (jint) {
            accf = iint ? vec4_cols<true >(eps, Hn, Wn, i0, j0, rd)
                        : vec4_cols<false>(eps, Hn, Wn, i0, j0, rd);
        } else {
            for (int c = 0; c < COLS_PER; ++c)
                if (j0 + c < Wn) accf += scalar_col(eps, Hn, Wn, i0, j0 + c, rd);
        }
    }

    double acc = (double)accf;
    #pragma unroll
    for (int off = 32; off > 0; off >>= 1)
        acc += __shfl_down(acc, off, 64);
    __shared__ double lds[BLOCK_X / 64];
    const int lane = tx & 63, wv = tx >> 6;
    if (lane == 0) lds[wv] = acc;
    __syncthreads();
    if (tx == 0) {
        // plain store — NO device-scope atomics
        partial[blockIdx.y * gridDim.x + blockIdx.x] =
            lds[0] + lds[1] + lds[2] + lds[3];
    }
}

__global__ __launch_bounds__(256) void curve_finish_kernel(
    const double* __restrict__ partial, int n,
    const float* __restrict__ gs, float* __restrict__ out)
{
    const int tx = threadIdx.x;
    double acc = 0.0;
    for (int idx = tx; idx < n; idx += 256) acc += partial[idx];
    #pragma unroll
    for (int off = 32; off > 0; off >>= 1)
        acc += __shfl_down(acc, off, 64);
    __shared__ double lds[4];
    const int lane = tx & 63, wv = tx >> 6;
    if (lane == 0) lds[wv] = acc;
    __syncthreads();
    if (tx == 0) {
        const double d = (double)gs[0];
        // x2 for the mirrored half; x d^2 for grid_size^2 (ALPHA=1)
        out[0] = (float)((lds[0] + lds[1] + lds[2] + lds[3]) * 2.0 * d * d);
    }
}

extern "C" void kernel_launch(void* const* d_in, const int* in_sizes, int n_in,
                              void* d_out, int out_size, void* d_ws, size_t ws_size,
                              hipStream_t stream) {
    const float* eps = (const float*)d_in[0];
    const float* gs  = (const float*)d_in[1];
    float* out = (float*)d_out;

    const int n = in_sizes[0];
    int Wn = (int)(sqrt((double)n) + 0.5);   // 4096 for 4096x4096
    int Hn = n / Wn;

    const int gx = (Wn + BLOCK_X * COLS_PER - 1) / (BLOCK_X * COLS_PER);  // 4
    const int gy = (Hn + ROWS_PER - 1) / ROWS_PER;                        // 512
    double* partial = (double*)d_ws;   // gx*gy slots, ALL written every launch

    curve_partial_kernel<<<dim3(gx, gy), BLOCK_X, 0, stream>>>(eps, gs, partial, Hn, Wn);
    curve_finish_kernel<<<1, 256, 0, stream>>>(partial, gx * gy, gs, out);
}

// Round 6
// 121.786 us; speedup vs baseline: 1.0459x; 1.0459x over previous
//
#include <hip/hip_runtime.h>
#include <math.h>

// fab_penalty_ls_curve: curvature penalty over mirrored level-set field.
// R6: R4 structure (13 batched loads/pt, ROWS_PER=16, plain partial stores,
// fast math) + hand strength-reduced addressing: 5 rotated row pointers with
// immediate column offsets replaces per-point 64-bit i*Wn muls (~75 -> ~12
// addressing ops/pt). Interior second derivatives folded (SC cancels).
// NO device-scope atomics (R2/R3 3x regression). Mirror-half trick: compute
// left half only, x2 (verified absmax 0.0).

#define BLOCK_X 256
#define ROWS_PER 16

// atan(v / c) with v > 0, given rv ~= 1/v (reused from k = num*rv^3).
// Max abs error ~1e-5 rad; error budget is ~1e3x larger (2% on the sum).
__device__ __forceinline__ float fast_atan_ratio(float v, float c, float rv)
{
    const float rc = __builtin_amdgcn_rcpf(c);
    const float q  = v * rc;        // v/c (sign = sign(c))
    const float iq = c * rv;        // c/v = 1/q, no extra rcp
    const bool  big = fabsf(q) > 1.0f;
    const float t  = big ? iq : q;
    const float s  = t * t;
    float p = fmaf(s, -0.01172120f, 0.05265332f);
    p = fmaf(s, p, -0.11643287f);
    p = fmaf(s, p,  0.19354346f);
    p = fmaf(s, p, -0.33262347f);
    p = fmaf(s, p,  0.99997726f);
    const float at = p * t;
    const float hp = copysignf(1.57079632679f, q);
    return big ? (hp - at) : at;    // atan(q) = sign(q)*pi/2 - atan(1/q), |q|>1
}

// Fully-interior path: rows [i0, i0+ROWS_PER) with i0>=2, i0+ROWS_PER+1 < Hn,
// and column j in [2, Wn-2). Row pointers rotate; column offsets are
// immediates. 13 independent loads per iteration (MLP preserved).
__device__ __forceinline__ float interior_rows(
    const float* __restrict__ eps, int Wn, int i0, int j, float rd2)
{
    const float SC = 1e-12f;
    const float FLOORV = (float)(1e-32 / 6.0);
    const float pi_d = 3.14159265358979323846f / 1.1f;
    const float rd22 = rd2 * rd2;

    const float* p0 = eps + (size_t)(i0 - 2) * (size_t)Wn + j;  // row i-2
    const float* p1 = p0 + Wn;                                  // row i-1
    const float* p2 = p1 + Wn;                                  // row i
    const float* p3 = p2 + Wn;                                  // row i+1
    const float* p4 = p3 + Wn;                                  // row i+2

    float acc = 0.0f;
    #pragma unroll
    for (int r = 0; r < ROWS_PER; ++r) {
        // 13 independent loads, all via row-pointer + immediate offset
        const float e_nn = p0[0];
        const float e_nw = p1[-1], e_n = p1[0], e_ne = p1[1];
        const float e_ww = p2[-2], e_w = p2[-1], e_c = p2[0],
                    e_e  = p2[1],  e_ee = p2[2];
        const float e_sw = p3[-1], e_s = p3[0], e_se = p3[1];
        const float e_ss = p4[0];

        const float ex = fmaf(e_s - e_n, rd2, SC);
        const float ey = fmaf(e_e - e_w, rd2, SC);
        // SC cancels in the second differences (folded interior forms)
        const float exx = fmaf(-2.0f, e_c, e_ss + e_nn) * rd22;
        const float eyy = fmaf(-2.0f, e_c, e_ee + e_ww) * rd22;
        const float exy = ((e_se - e_ne) - (e_sw - e_nw)) * rd22;

        const float t1 = ex * ex;
        const float t2 = ey * ey;
        const float exy2 = exy + exy;
        float num = t1 * eyy;
        num = fmaf(t2, exx, num);
        num = fmaf(-(ex * ey), exy2, num);

        float ev = __builtin_amdgcn_sqrtf(t1 + t2);
        ev = fmaxf(ev, FLOORV);
        const float rv = __builtin_amdgcn_rcpf(ev);
        const float k  = num * (rv * rv) * rv;
        const float at = fast_atan_ratio(ev, e_c, rv);
        const float cc = fabsf(k * at) - pi_d;
        acc += fmaxf(cc, 0.0f);      // fmax(NaN,0)=0 -> nansum semantics

        // rotate row pointers (full unroll -> static renames + one add chain)
        p0 = p1; p1 = p2; p2 = p3; p3 = p4; p4 += Wn;
    }
    return acc;
}

// Generic path: handles row clamps (one-sided diffs) and column clamp/mirror.
// Used for the 2 boundary row-blocks and the 2 edge lanes per edge wave.
__device__ float generic_rows(const float* __restrict__ eps, int Hn, int Wn,
                              int i0, int j, float rd)
{
    const float rd2 = 0.5f * rd;
    const float SC = 1e-12f;
    const float FLOORV = (float)(1e-32 / 6.0);
    const float pi_d = 3.14159265358979323846f / 1.1f;

    const int jm  = (j > 0) ? j - 1 : 0;
    const int jmm = (j > 1) ? j - 2 : 0;
    const int jp = j + 1, jpp = j + 2;
    const int cjp  = (jp  < Wn) ? jp  : (2 * Wn - 1 - jp);   // mirror seam
    const int cjpp = (jpp < Wn) ? jpp : (2 * Wn - 1 - jpp);
    const float syj = (j == 0)  ? rd : rd2;
    const float sym = (jm == 0) ? rd : rd2;
    const float syp = rd2;   // jp never a boundary of the 2W virtual grid

    float acc = 0.0f;
    for (int r = 0; r < ROWS_PER; ++r) {
        const int i = i0 + r;
        if (i >= Hn) break;
        const int im  = (i > 0) ? i - 1 : 0;
        const int ip  = (i < Hn - 1) ? i + 1 : Hn - 1;
        const int imm = (im > 0) ? im - 1 : 0;
        const int ipp = (ip < Hn - 1) ? ip + 1 : Hn - 1;
        const float sxi = (i == 0 || i == Hn - 1) ? rd : rd2;
        const float sxm = (im == 0) ? rd : rd2;
        const float sxp = (ip == Hn - 1) ? rd : rd2;

        const float* rowc  = eps + (size_t)i   * (size_t)Wn;
        const float* rown  = eps + (size_t)im  * (size_t)Wn;
        const float* rows_ = eps + (size_t)ip  * (size_t)Wn;
        const float* rownn = eps + (size_t)imm * (size_t)Wn;
        const float* rowss = eps + (size_t)ipp * (size_t)Wn;

        const float e_c  = rowc[j];
        const float e_n  = rown[j],   e_s  = rows_[j];
        const float e_nn = rownn[j],  e_ss = rowss[j];
        const float e_w  = rowc[jm],  e_e  = rowc[cjp];
        const float e_ww = rowc[jmm], e_ee = rowc[cjpp];
        const float e_nw = rown[jm],  e_ne = rown[cjp];
        const float e_sw = rows_[jm], e_se = rows_[cjp];

        const float ex = fmaf(e_s - e_n, sxi, SC);
        const float ey = fmaf(e_e - e_w, syj, SC);
        float exn = fmaf(e_c - e_nn, sxm, SC);
        float exs = fmaf(e_ss - e_c, sxp, SC);
        if (i == 0)      exn = ex;
        if (i == Hn - 1) exs = ex;
        const float exx = (exs - exn) * sxi;
        float eyw = fmaf(e_c - e_ww, sym, SC);
        const float eye = fmaf(e_ee - e_c, syp, SC);
        if (j == 0) eyw = ey;
        const float eyy = (eye - eyw) * syj;
        const float exy = ((e_se - e_ne) - (e_sw - e_nw)) * (sxi * syj);

        const float t1 = ex * ex;
        const float t2 = ey * ey;
        float num = t1 * eyy;
        num = fmaf(t2, exx, num);
        num = fmaf(-2.0f * (ex * ey), exy, num);

        float ev = __builtin_amdgcn_sqrtf(t1 + t2);
        ev = fmaxf(ev, FLOORV);
        const float rv = __builtin_amdgcn_rcpf(ev);
        const float k  = num * (rv * rv) * rv;
        const float at = fast_atan_ratio(ev, e_c, rv);
        const float cc = fabsf(k * at) - pi_d;
        acc += fmaxf(cc, 0.0f);
    }
    return acc;
}

__global__ __launch_bounds__(BLOCK_X, 4) void curve_partial_kernel(
    const float* __restrict__ eps, const float* __restrict__ gs,
    double* __restrict__ partial, int Hn, int Wn)
{
    const int tx = threadIdx.x;
    const int j  = blockIdx.x * BLOCK_X + tx;
    const int i0 = blockIdx.y * ROWS_PER;
    const float rd = 1.0f / gs[0];
    const float rd2 = 0.5f * rd;

    float accf;
    const bool row_int = (i0 >= 2) && (i0 + ROWS_PER + 1 < Hn);
    const bool col_int = (j >= 2) && (j + 2 < Wn);
    if (row_int && col_int)
        accf = interior_rows(eps, Wn, i0, j, rd2);
    else
        accf = generic_rows(eps, Hn, Wn, i0, j, rd);

    double acc = (double)accf;
    #pragma unroll
    for (int off = 32; off > 0; off >>= 1)
        acc += __shfl_down(acc, off, 64);
    __shared__ double lds[BLOCK_X / 64];
    const int lane = tx & 63, wv = tx >> 6;
    if (lane == 0) lds[wv] = acc;
    __syncthreads();
    if (tx == 0) {
        // plain store — NO device-scope atomics
        partial[blockIdx.y * gridDim.x + blockIdx.x] =
            lds[0] + lds[1] + lds[2] + lds[3];
    }
}

__global__ __launch_bounds__(256) void curve_finish_kernel(
    const double* __restrict__ partial, int n,
    const float* __restrict__ gs, float* __restrict__ out)
{
    const int tx = threadIdx.x;
    double acc = 0.0;
    for (int idx = tx; idx < n; idx += 256) acc += partial[idx];
    #pragma unroll
    for (int off = 32; off > 0; off >>= 1)
        acc += __shfl_down(acc, off, 64);
    __shared__ double lds[4];
    const int lane = tx & 63, wv = tx >> 6;
    if (lane == 0) lds[wv] = acc;
    __syncthreads();
    if (tx == 0) {
        const double d = (double)gs[0];
        // x2 for the mirrored half; x d^2 for grid_size^2 (ALPHA=1)
        out[0] = (float)((lds[0] + lds[1] + lds[2] + lds[3]) * 2.0 * d * d);
    }
}

extern "C" void kernel_launch(void* const* d_in, const int* in_sizes, int n_in,
                              void* d_out, int out_size, void* d_ws, size_t ws_size,
                              hipStream_t stream) {
    const float* eps = (const float*)d_in[0];
    const float* gs  = (const float*)d_in[1];
    float* out = (float*)d_out;

    const int n = in_sizes[0];
    int Wn = (int)(sqrt((double)n) + 0.5);   // 4096 for 4096x4096
    int Hn = n / Wn;

    const int gx = (Wn + BLOCK_X - 1) / BLOCK_X;     // 16
    const int gy = (Hn + ROWS_PER - 1) / ROWS_PER;   // 256
    double* partial = (double*)d_ws;   // gx*gy slots, ALL written every launch

    curve_partial_kernel<<<dim3(gx, gy), BLOCK_X, 0, stream>>>(eps, gs, partial, Hn, Wn);
    curve_finish_kernel<<<1, 256, 0, stream>>>(partial, gx * gy, gs, out);
}

// Round 7
// 120.752 us; speedup vs baseline: 1.0549x; 1.0086x over previous
//
#include <hip/hip_runtime.h>
#include <math.h>

// fab_penalty_ls_curve: curvature penalty over mirrored level-set field.
// R7: LDS-staged stencil tile. R6 was co-limited by L1 BW (13 loads/pt x
// 256B/wave-load ~= 700 cyc/CU/round == VALU 700 cyc -> VALUBusy 48%).
// Stage 260x20 tile (20.8KB) once per block (~1.3 coalesced loads/pt), then
// 13 ds_read_b32 per point via ONE v_addr + immediate offsets (zero address
// VALU). Stride-1 LDS = 2 lanes/bank = free. Mirror staging makes the right
// seam exact so LDS path covers j in [2, Wn). Fast math + plain partial
// stores kept (device-scope atomic finish was R2/R3's 3x regression).
// Mirror-half trick: compute left half only, x2 (verified absmax 0.0).

#define BLOCK_X 256
#define ROWS_PER 16
#define TILE_W (BLOCK_X + 4)      // 260
#define TILE_H (ROWS_PER + 4)     // 20

// atan(v / c) with v > 0, given rv ~= 1/v (reused from k = num*rv^3).
// Max abs error ~1e-5 rad; error budget is ~1e3x larger (2% on the sum).
__device__ __forceinline__ float fast_atan_ratio(float v, float c, float rv)
{
    const float rc = __builtin_amdgcn_rcpf(c);
    const float q  = v * rc;        // v/c (sign = sign(c))
    const float iq = c * rv;        // c/v = 1/q, no extra rcp
    const bool  big = fabsf(q) > 1.0f;
    const float t  = big ? iq : q;
    const float s  = t * t;
    float p = fmaf(s, -0.01172120f, 0.05265332f);
    p = fmaf(s, p, -0.11643287f);
    p = fmaf(s, p,  0.19354346f);
    p = fmaf(s, p, -0.33262347f);
    p = fmaf(s, p,  0.99997726f);
    const float at = p * t;
    const float hp = copysignf(1.57079632679f, q);
    return big ? (hp - at) : at;    // atan(q) = sign(q)*pi/2 - atan(1/q), |q|>1
}

// Interior math from the LDS tile. Output row r -> tile row r+2; thread col
// tx -> tile col tx+2. All 13 reads share v_addr (=&tile[tx]) + immediates.
__device__ __forceinline__ float lds_rows(const float* __restrict__ tile,
                                          int tx, float rd2)
{
    const float SC = 1e-12f;
    const float FLOORV = (float)(1e-32 / 6.0);
    const float pi_d = 3.14159265358979323846f / 1.1f;
    const float rd22 = rd2 * rd2;

    float acc = 0.0f;
    #pragma unroll
    for (int r = 0; r < ROWS_PER; ++r) {
        const float e_nn = tile[(r + 0) * TILE_W + tx + 2];
        const float e_nw = tile[(r + 1) * TILE_W + tx + 1];
        const float e_n  = tile[(r + 1) * TILE_W + tx + 2];
        const float e_ne = tile[(r + 1) * TILE_W + tx + 3];
        const float e_ww = tile[(r + 2) * TILE_W + tx + 0];
        const float e_w  = tile[(r + 2) * TILE_W + tx + 1];
        const float e_c  = tile[(r + 2) * TILE_W + tx + 2];
        const float e_e  = tile[(r + 2) * TILE_W + tx + 3];
        const float e_ee = tile[(r + 2) * TILE_W + tx + 4];
        const float e_sw = tile[(r + 3) * TILE_W + tx + 1];
        const float e_s  = tile[(r + 3) * TILE_W + tx + 2];
        const float e_se = tile[(r + 3) * TILE_W + tx + 3];
        const float e_ss = tile[(r + 4) * TILE_W + tx + 2];

        const float ex = fmaf(e_s - e_n, rd2, SC);
        const float ey = fmaf(e_e - e_w, rd2, SC);
        // SC cancels in the second differences (folded interior forms)
        const float exx = fmaf(-2.0f, e_c, e_ss + e_nn) * rd22;
        const float eyy = fmaf(-2.0f, e_c, e_ee + e_ww) * rd22;
        const float exy = ((e_se - e_ne) - (e_sw - e_nw)) * rd22;

        const float t1 = ex * ex;
        const float t2 = ey * ey;
        const float exy2 = exy + exy;
        float num = t1 * eyy;
        num = fmaf(t2, exx, num);
        num = fmaf(-(ex * ey), exy2, num);

        float ev = __builtin_amdgcn_sqrtf(t1 + t2);
        ev = fmaxf(ev, FLOORV);
        const float rv = __builtin_amdgcn_rcpf(ev);
        const float k  = num * (rv * rv) * rv;
        const float at = fast_atan_ratio(ev, e_c, rv);
        const float cc = fabsf(k * at) - pi_d;
        acc += fmaxf(cc, 0.0f);      // fmax(NaN,0)=0 -> nansum semantics
    }
    return acc;
}

// Generic path: row clamps (one-sided diffs) and column clamp/mirror.
// Used for y-edge blocks and the j=0,1 lanes of the x=0 block.
__device__ float generic_rows(const float* __restrict__ eps, int Hn, int Wn,
                              int i0, int j, float rd)
{
    const float rd2 = 0.5f * rd;
    const float SC = 1e-12f;
    const float FLOORV = (float)(1e-32 / 6.0);
    const float pi_d = 3.14159265358979323846f / 1.1f;

    const int jm  = (j > 0) ? j - 1 : 0;
    const int jmm = (j > 1) ? j - 2 : 0;
    const int jp = j + 1, jpp = j + 2;
    const int cjp  = (jp  < Wn) ? jp  : (2 * Wn - 1 - jp);   // mirror seam
    const int cjpp = (jpp < Wn) ? jpp : (2 * Wn - 1 - jpp);
    const float syj = (j == 0)  ? rd : rd2;
    const float sym = (jm == 0) ? rd : rd2;
    const float syp = rd2;   // jp never a boundary of the 2W virtual grid

    float acc = 0.0f;
    for (int r = 0; r < ROWS_PER; ++r) {
        const int i = i0 + r;
        if (i >= Hn) break;
        const int im  = (i > 0) ? i - 1 : 0;
        const int ip  = (i < Hn - 1) ? i + 1 : Hn - 1;
        const int imm = (im > 0) ? im - 1 : 0;
        const int ipp = (ip < Hn - 1) ? ip + 1 : Hn - 1;
        const float sxi = (i == 0 || i == Hn - 1) ? rd : rd2;
        const float sxm = (im == 0) ? rd : rd2;
        const float sxp = (ip == Hn - 1) ? rd : rd2;

        const float* rowc  = eps + (size_t)i   * (size_t)Wn;
        const float* rown  = eps + (size_t)im  * (size_t)Wn;
        const float* rows_ = eps + (size_t)ip  * (size_t)Wn;
        const float* rownn = eps + (size_t)imm * (size_t)Wn;
        const float* rowss = eps + (size_t)ipp * (size_t)Wn;

        const float e_c  = rowc[j];
        const float e_n  = rown[j],   e_s  = rows_[j];
        const float e_nn = rownn[j],  e_ss = rowss[j];
        const float e_w  = rowc[jm],  e_e  = rowc[cjp];
        const float e_ww = rowc[jmm], e_ee = rowc[cjpp];
        const float e_nw = rown[jm],  e_ne = rown[cjp];
        const float e_sw = rows_[jm], e_se = rows_[cjp];

        const float ex = fmaf(e_s - e_n, sxi, SC);
        const float ey = fmaf(e_e - e_w, syj, SC);
        float exn = fmaf(e_c - e_nn, sxm, SC);
        float exs = fmaf(e_ss - e_c, sxp, SC);
        if (i == 0)      exn = ex;
        if (i == Hn - 1) exs = ex;
        const float exx = (exs - exn) * sxi;
        float eyw = fmaf(e_c - e_ww, sym, SC);
        const float eye = fmaf(e_ee - e_c, syp, SC);
        if (j == 0) eyw = ey;
        const float eyy = (eye - eyw) * syj;
        const float exy = ((e_se - e_ne) - (e_sw - e_nw)) * (sxi * syj);

        const float t1 = ex * ex;
        const float t2 = ey * ey;
        float num = t1 * eyy;
        num = fmaf(t2, exx, num);
        num = fmaf(-2.0f * (ex * ey), exy, num);

        float ev = __builtin_amdgcn_sqrtf(t1 + t2);
        ev = fmaxf(ev, FLOORV);
        const float rv = __builtin_amdgcn_rcpf(ev);
        const float k  = num * (rv * rv) * rv;
        const float at = fast_atan_ratio(ev, e_c, rv);
        const float cc = fabsf(k * at) - pi_d;
        acc += fmaxf(cc, 0.0f);
    }
    return acc;
}

__global__ __launch_bounds__(BLOCK_X) void curve_partial_kernel(
    const float* __restrict__ eps, const float* __restrict__ gs,
    double* __restrict__ partial, int Hn, int Wn)
{
    __shared__ float tile[TILE_H * TILE_W];
    const int tx = threadIdx.x;
    const int jb = blockIdx.x * BLOCK_X;
    const int j  = jb + tx;
    const int i0 = blockIdx.y * ROWS_PER;
    const float rd = 1.0f / gs[0];
    const float rd2 = 0.5f * rd;

    // staged rows i0-2 .. i0+ROWS_PER+1 must all be in-bounds
    const bool row_int = (i0 >= 2) && (i0 + ROWS_PER + 2 <= Hn);

    float accf = 0.0f;
    if (row_int) {
        // ---- stage 260 x 20 tile (rows are interior; cols may clamp/mirror)
        const bool cint = (jb >= 2) && (jb + BLOCK_X + 2 <= Wn);
        const float* g = eps + (size_t)(i0 - 2) * (size_t)Wn;
        if (cint) {
            const float* gm = g + (jb - 2) + tx;
            float buf[TILE_H];
            #pragma unroll
            for (int r = 0; r < TILE_H; ++r) buf[r] = gm[(size_t)r * Wn];
            #pragma unroll
            for (int r = 0; r < TILE_H; ++r) tile[r * TILE_W + tx] = buf[r];
            if (tx < 4) {
                const float* gt = gm + BLOCK_X;
                float bt[TILE_H];
                #pragma unroll
                for (int r = 0; r < TILE_H; ++r) bt[r] = gt[(size_t)r * Wn];
                #pragma unroll
                for (int r = 0; r < TILE_H; ++r)
                    tile[r * TILE_W + BLOCK_X + tx] = bt[r];
            }
        } else {
            int c0 = jb - 2 + tx;                      // main column
            c0 = (c0 < 0) ? 0 : ((c0 >= Wn) ? 2 * Wn - 1 - c0 : c0);
            float buf[TILE_H];
            #pragma unroll
            for (int r = 0; r < TILE_H; ++r) buf[r] = g[(size_t)r * Wn + c0];
            #pragma unroll
            for (int r = 0; r < TILE_H; ++r) tile[r * TILE_W + tx] = buf[r];
            if (tx < 4) {
                int c1 = jb + 2 + BLOCK_X + tx - 4 + 2;  // = jb+254+tx
                c1 = (c1 < 0) ? 0 : ((c1 >= Wn) ? 2 * Wn - 1 - c1 : c1);
                float bt[TILE_H];
                #pragma unroll
                for (int r = 0; r < TILE_H; ++r) bt[r] = g[(size_t)r * Wn + c1];
                #pragma unroll
                for (int r = 0; r < TILE_H; ++r)
                    tile[r * TILE_W + BLOCK_X + tx] = bt[r];
            }
        }
        __syncthreads();

        if (j >= 2 && j < Wn)        // right seam exact via mirror staging
            accf = lds_rows(tile, tx, rd2);
        else if (j < Wn)             // j = 0,1 lanes of block x==0
            accf = generic_rows(eps, Hn, Wn, i0, j, rd);
    } else {
        if (j < Wn)
            accf = generic_rows(eps, Hn, Wn, i0, j, rd);
    }

    double acc = (double)accf;
    #pragma unroll
    for (int off = 32; off > 0; off >>= 1)
        acc += __shfl_down(acc, off, 64);
    __shared__ double ldsr[BLOCK_X / 64];
    const int lane = tx & 63, wv = tx >> 6;
    if (lane == 0) ldsr[wv] = acc;
    __syncthreads();
    if (tx == 0) {
        // plain store — NO device-scope atomics
        partial[blockIdx.y * gridDim.x + blockIdx.x] =
            ldsr[0] + ldsr[1] + ldsr[2] + ldsr[3];
    }
}

__global__ __launch_bounds__(256) void curve_finish_kernel(
    const double* __restrict__ partial, int n,
    const float* __restrict__ gs, float* __restrict__ out)
{
    const int tx = threadIdx.x;
    double acc = 0.0;
    for (int idx = tx; idx < n; idx += 256) acc += partial[idx];
    #pragma unroll
    for (int off = 32; off > 0; off >>= 1)
        acc += __shfl_down(acc, off, 64);
    __shared__ double lds[4];
    const int lane = tx & 63, wv = tx >> 6;
    if (lane == 0) lds[wv] = acc;
    __syncthreads();
    if (tx == 0) {
        const double d = (double)gs[0];
        // x2 for the mirrored half; x d^2 for grid_size^2 (ALPHA=1)
        out[0] = (float)((lds[0] + lds[1] + lds[2] + lds[3]) * 2.0 * d * d);
    }
}

extern "C" void kernel_launch(void* const* d_in, const int* in_sizes, int n_in,
                              void* d_out, int out_size, void* d_ws, size_t ws_size,
                              hipStream_t stream) {
    const float* eps = (const float*)d_in[0];
    const float* gs  = (const float*)d_in[1];
    float* out = (float*)d_out;

    const int n = in_sizes[0];
    int Wn = (int)(sqrt((double)n) + 0.5);   // 4096 for 4096x4096
    int Hn = n / Wn;

    const int gx = (Wn + BLOCK_X - 1) / BLOCK_X;     // 16
    const int gy = (Hn + ROWS_PER - 1) / ROWS_PER;   // 256
    double* partial = (double*)d_ws;   // gx*gy slots, ALL written every launch

    curve_partial_kernel<<<dim3(gx, gy), BLOCK_X, 0, stream>>>(eps, gs, partial, Hn, Wn);
    curve_finish_kernel<<<1, 256, 0, stream>>>(partial, gx * gy, gs, out);
}